// Round 13
// baseline (129.858 us; speedup 1.0000x reference)
//
#include <hip/hip_runtime.h>

#define D 1536
#define BT 96          // square output tile
#define BK 64          // K-step
#define NT (D / BK)    // 24 K-steps
#define TT 64
#define TILE_E (BT * BK)       // 6144 elements per staged tile (12 KiB)
#define BUF_E (3 * TILE_E)     // A | Bs | Bd per buffer (36 KiB)

typedef unsigned short u16;
typedef short bf16x8 __attribute__((ext_vector_type(8)));
typedef float f32x4 __attribute__((ext_vector_type(4)));

static __device__ __forceinline__ u16 f2bf(float f) {
    unsigned u; __builtin_memcpy(&u, &f, 4);
    unsigned r = (u + 0x7FFFu + ((u >> 16) & 1u)) >> 16;
    return (u16)r;
}
static __device__ __forceinline__ float bf2f(u16 s) {
    unsigned u = ((unsigned)s) << 16;
    float f; __builtin_memcpy(&f, &u, 4); return f;
}

#define GLDS(g, s) __builtin_amdgcn_global_load_lds( \
    (const __attribute__((address_space(1))) void*)(g), \
    (__attribute__((address_space(3))) void*)(s), 16, 0, 0)

#define MFMA16(a, b, c) __builtin_amdgcn_mfma_f32_16x16x32_bf16(a, b, c, 0, 0, 0)

// ---------------- prep ----------------
// z=0..2: layer z: BsT[z] = bf16((ucs[z]+lcs[z])/2)^T, BdT[z] = bf16((ucs[z]-lcs[z])/2)^T
// z=3:    convert ucs[3]->Ga, lcs[3]->Gc (bf16, untransposed)
__global__ __launch_bounds__(256) void prep_k(
    const float* __restrict__ lcs, const float* __restrict__ ucs,
    u16* __restrict__ BsT, u16* __restrict__ BdT,
    u16* __restrict__ Ga, u16* __restrict__ Gc)
{
    const int z = blockIdx.z;
    const int r0 = blockIdx.y * TT, c0 = blockIdx.x * TT;
    const int tid = threadIdx.x;

    if (z == 3) {
#pragma unroll
        for (int m = 0; m < 2; ++m) {
            const float* src = (m ? lcs : ucs) + (size_t)3 * D * D;
            u16* dst = m ? Gc : Ga;
#pragma unroll
            for (int i = 0; i < 2; ++i) {
                int r = (tid >> 3) + i * 32, cc = (tid & 7) * 8;
                const float* p = src + (size_t)(r0 + r) * D + c0 + cc;
                f32x4 x0 = *(const f32x4*)p;
                f32x4 x1 = *(const f32x4*)(p + 4);
                bf16x8 y;
#pragma unroll
                for (int e = 0; e < 4; ++e) { y[e] = (short)f2bf(x0[e]); y[e + 4] = (short)f2bf(x1[e]); }
                *(bf16x8*)(dst + (size_t)(r0 + r) * D + c0 + cc) = y;
            }
        }
        return;
    }

    __shared__ u16 ts[TT][TT + 8];
    __shared__ u16 td[TT][TT + 8];
    const float* srcl = lcs + (size_t)z * D * D;
    const float* srcu = ucs + (size_t)z * D * D;
#pragma unroll
    for (int i = 0; i < 2; ++i) {
        int c = tid + i * 256; int r = c >> 3, v = c & 7;
        size_t off = (size_t)(r0 + r) * D + c0 + v * 8;
        f32x4 l0 = *(const f32x4*)(srcl + off);
        f32x4 l1 = *(const f32x4*)(srcl + off + 4);
        f32x4 u0 = *(const f32x4*)(srcu + off);
        f32x4 u1 = *(const f32x4*)(srcu + off + 4);
        bf16x8 ys, yd;
#pragma unroll
        for (int e = 0; e < 4; ++e) {
            ys[e]     = (short)f2bf((u0[e] + l0[e]) * 0.5f);
            yd[e]     = (short)f2bf((u0[e] - l0[e]) * 0.5f);
            ys[e + 4] = (short)f2bf((u1[e] + l1[e]) * 0.5f);
            yd[e + 4] = (short)f2bf((u1[e] - l1[e]) * 0.5f);
        }
        *(bf16x8*)&ts[r][v * 8] = ys;
        *(bf16x8*)&td[r][v * 8] = yd;
    }
    __syncthreads();
#pragma unroll
    for (int i = 0; i < 2; ++i) {
        int c = tid + i * 256; int rr = c >> 3, v = c & 7;
        bf16x8 xs, xd;
#pragma unroll
        for (int e = 0; e < 8; ++e) { xs[e] = (short)ts[v * 8 + e][rr]; xd[e] = (short)td[v * 8 + e][rr]; }
        size_t off = (size_t)z * D * D + (size_t)(c0 + rr) * D + r0 + v * 8;
        *(bf16x8*)(BsT + off) = xs;
        *(bf16x8*)(BdT + off) = xd;
    }
}

// ---------------- vec: lb0/ub0 rows + cb init (layer-3 bias + j=2 bias update), all f32 ----------------
__global__ __launch_bounds__(256) void vec_k(
    const float* __restrict__ lb, const float* __restrict__ ub,
    const float* __restrict__ lcs, const float* __restrict__ ucs,
    const float* __restrict__ lcb, const float* __restrict__ ucb,
    float* __restrict__ lb0, float* __restrict__ ub0,
    float* __restrict__ cb_uc, float* __restrict__ cb_lc)
{
    const int tt = blockIdx.x * 4 + (threadIdx.x >> 6);
    const int lane = threadIdx.x & 63;
    const int which = tt / D;           // 0:lb0 1:ub0 2:cb_uc 3:cb_lc
    const int row_n = tt - which * D;

    const float* row; const float* vp; const float* vn;
    if (which == 0)      { row = lcs + (size_t)row_n * D;               vp = lb;           vn = ub; }
    else if (which == 1) { row = ucs + (size_t)row_n * D;               vp = ub;           vn = lb; }
    else if (which == 2) { row = ucs + (size_t)(3 * (size_t)D * D) + (size_t)row_n * D; vp = ucb + 2 * D; vn = lcb + 2 * D; }
    else                 { row = lcs + (size_t)(3 * (size_t)D * D) + (size_t)row_n * D; vp = lcb + 2 * D; vn = ucb + 2 * D; }

    float s = 0.f;
    for (int c2 = 0; c2 < D / 256; ++c2) {
        int base = (c2 * 64 + lane) * 4;
        f32x4 g = *(const f32x4*)(row + base);
        f32x4 p = *(const f32x4*)(vp + base);
        f32x4 m = *(const f32x4*)(vn + base);
#pragma unroll
        for (int e = 0; e < 4; ++e) s += g[e] * (g[e] > 0.f ? p[e] : m[e]);
    }
#pragma unroll
    for (int o = 32; o; o >>= 1) s += __shfl_down(s, o);
    if (lane == 0) {
        if (which == 0)      lb0[row_n] = s + lcb[row_n];
        else if (which == 1) ub0[row_n] = s + ucb[row_n];
        else if (which == 2) cb_uc[row_n] = s + ucb[3 * D + row_n];
        else                 cb_lc[row_n] = s + lcb[3 * D + row_n];
    }
}

// ---------------- GEMM step: out = A@Bs + sgn(|A|)@Bd ----------------
// chain 0 (uc): out = Guc@Bs + |Guc|@Bd ; chain 1 (lc): out = Glc@Bs - |Glc|@Bd.
// 96x96 tile, 4 waves (2x2), per-wave 48x48. Double-buffered LDS with counted
// vmcnt (2-deep prefetch), one stage per K-step (R6-proven schedule).
// XOR swizzle slot^(row&7) via pre-swizzled global source (rule #21).
// XCD-aware block swizzle (R9). Epilogue: rowdot(acc, vp/vn) -> atomicAdd cb.
// For j>0 the vectors are the next layer's biases (bias recurrence); for j=0
// they are ub0/lb0 (the final apply, in f32 from acc) and stores are skipped.
__global__ __launch_bounds__(256, 2) void gemm_step(
    const u16* __restrict__ Guc, const u16* __restrict__ Glc,
    const u16* __restrict__ Bs, const u16* __restrict__ Bd,
    u16* __restrict__ outU, u16* __restrict__ outL,
    const float* __restrict__ ucbN, const float* __restrict__ lcbN,
    float* __restrict__ cb_uc, float* __restrict__ cb_lc)
{
    __shared__ u16 smem[2 * BUF_E];          // 2 x 36 KiB
    // ---- XCD swizzle: wgid linear (x fastest) -> (bx, by, chain) ----
    const int wg  = blockIdx.x + 16 * blockIdx.y + 256 * blockIdx.z;  // 0..511
    const int xcd = wg & 7, idx = wg >> 3;                            // 64 wgs per XCD
    const int chain = xcd >> 2;
    const int bx = (xcd & 1) * 8 + (idx & 7);
    const int by = ((xcd >> 1) & 1) * 8 + (idx >> 3);

    const u16* A = chain ? Glc : Guc;
    u16* out = chain ? outL : outU;
    const unsigned sgn = chain ? 0x80008000u : 0u;   // -|A| for lc chain
    const int r0 = by * BT, c0 = bx * BT;
    const int tid = threadIdx.x, lane = tid & 63, wid = tid >> 6;
    const int mb = (wid >> 1) * 48, nb = (wid & 1) * 48;
    const int lrow = lane & 15, lk = lane >> 4;

    f32x4 acc[3][3] = {};

    // staging: 9 chunks of 16B per thread; chunk c=(i%3)*256+tid -> row c>>3,
    // kc=tid&7, global k-slot pre-swizzled kcg = kc ^ (row&7)
#define STAGE(kt, sbuf) do { \
    _Pragma("unroll") for (int i_ = 0; i_ < 9; ++i_) { \
        const int idx_ = (i_ % 3) * 256 + tid; \
        const int row_ = idx_ >> 3; \
        const int kcg_ = (tid & 7) ^ (row_ & 7); \
        const u16* base_ = (i_ < 3) ? (A + (size_t)(r0 + row_) * D) \
                        : ((i_ < 6) ? (Bs + (size_t)(c0 + row_) * D) \
                                    : (Bd + (size_t)(c0 + row_) * D)); \
        GLDS(base_ + (kt) + kcg_ * 8, (char*)(sbuf) + (i_ * 256 + wid * 64) * 16); \
    } } while (0)

    // prologue: stage tiles 0 and 1 (9+9 outstanding per wave)
    STAGE(0, smem);
    STAGE(BK, smem + BUF_E);

#pragma unroll 1
    for (int t = 0; t < NT; ++t) {
        if (t < NT - 1) { asm volatile("s_waitcnt vmcnt(9)" ::: "memory"); }
        else            { asm volatile("s_waitcnt vmcnt(0)" ::: "memory"); }
        __builtin_amdgcn_sched_barrier(0);
        __builtin_amdgcn_s_barrier();        // tile t visible to all waves

        const u16* sb = smem + (t & 1) * BUF_E;
#pragma unroll
        for (int ks = 0; ks < 2; ++ks) {
            const int slot = ks * 4;
            bf16x8 a[3], x[3];
#pragma unroll
            for (int mi = 0; mi < 3; ++mi) {
                int row = mb + mi * 16 + lrow;
                a[mi] = *(const bf16x8*)(sb + row * BK + ((slot + lk) ^ (row & 7)) * 8);
                union { bf16x8 v; unsigned u[4]; } ti, to;
                ti.v = a[mi];
#pragma unroll
                for (int q = 0; q < 4; ++q) to.u[q] = (ti.u[q] & 0x7FFF7FFFu) ^ sgn;
                x[mi] = to.v;
            }
#pragma unroll
            for (int ni = 0; ni < 3; ++ni) {
                int row = nb + ni * 16 + lrow;
                int o = row * BK + ((slot + lk) ^ (row & 7)) * 8;
                bf16x8 bs = *(const bf16x8*)(sb + TILE_E + o);
                bf16x8 bd = *(const bf16x8*)(sb + 2 * TILE_E + o);
#pragma unroll
                for (int mi = 0; mi < 3; ++mi) {
                    acc[mi][ni] = MFMA16(a[mi], bs, acc[mi][ni]);
                    acc[mi][ni] = MFMA16(x[mi], bd, acc[mi][ni]);
                }
            }
        }
        __builtin_amdgcn_s_barrier();        // all waves done reading buf[t&1]
        if (t + 2 < NT)
            STAGE((t + 2) * BK, smem + (t & 1) * BUF_E);
    }

    // fused epilogue: rowdot(acc, select(vp,vn)) accumulated into cb.
    // j>0: vp/vn = next layer's biases (bias recurrence).
    // j=0: vp/vn = ub0/lb0 (final apply), f32-exact from accumulators.
    {
        const float* pb_ = chain ? lcbN : ucbN;
        const float* nb_ = chain ? ucbN : lcbN;
        float* cb = chain ? cb_lc : cb_uc;
        float pbv[3], nbv[3];
#pragma unroll
        for (int ni = 0; ni < 3; ++ni) {
            int c = c0 + nb + ni * 16 + lrow;
            pbv[ni] = pb_[c]; nbv[ni] = nb_[c];
        }
#pragma unroll
        for (int mi = 0; mi < 3; ++mi)
#pragma unroll
            for (int q = 0; q < 4; ++q) {
                float s = 0.f;
#pragma unroll
                for (int ni = 0; ni < 3; ++ni) {
                    float g = acc[mi][ni][q];
                    s += g * (g > 0.f ? pbv[ni] : nbv[ni]);
                }
                s += __shfl_xor(s, 1); s += __shfl_xor(s, 2);
                s += __shfl_xor(s, 4); s += __shfl_xor(s, 8);
                if (lrow == 0)
                    atomicAdd(&cb[r0 + mb + mi * 16 + lk * 4 + q], s);
            }
    }

    if (out) {
#pragma unroll
        for (int mi = 0; mi < 3; ++mi)
#pragma unroll
            for (int ni = 0; ni < 3; ++ni) {
                int c = c0 + nb + ni * 16 + lrow;
                int rbase = r0 + mb + mi * 16 + lk * 4;
#pragma unroll
                for (int q = 0; q < 4; ++q)
                    out[(size_t)(rbase + q) * D + c] = f2bf(acc[mi][ni][q]);
            }
    }
#undef STAGE
}

// ---------------- emit: out[0..D) = cb_lc (cur_lb), out[D..2D) = cb_uc (cur_ub) ----------------
__global__ __launch_bounds__(256) void emit_k(
    const float* __restrict__ cb_uc, const float* __restrict__ cb_lc,
    float* __restrict__ out)
{
    int i = blockIdx.x * 256 + threadIdx.x;
    if (i < D)          out[i] = cb_lc[i];
    else if (i < 2 * D) out[i] = cb_uc[i - D];
}

extern "C" void kernel_launch(void* const* d_in, const int* in_sizes, int n_in,
                              void* d_out, int out_size, void* d_ws, size_t ws_size,
                              hipStream_t stream) {
    const float* lb  = (const float*)d_in[0];
    const float* ub  = (const float*)d_in[1];
    const float* lcs = (const float*)d_in[2];
    const float* ucs = (const float*)d_in[3];
    const float* lcb = (const float*)d_in[4];
    const float* ucb = (const float*)d_in[5];
    float* out = (float*)d_out;

    const size_t DD = (size_t)D * D;
    u16* ws   = (u16*)d_ws;
    u16* BsT = ws;                  // 3*D*D bf16, [N][K] layout
    u16* BdT = BsT + 3 * DD;        // 3*D*D bf16
    u16* Ga = BdT + 3 * DD;         // G ping-pong buffers (bf16)
    u16* Gb = Ga + DD;
    u16* Gc = Gb + DD;
    u16* Gd = Gc + DD;
    float* fbuf  = (float*)(Gd + DD);
    float* lb0   = fbuf;
    float* ub0   = fbuf + D;
    float* cb_uc = fbuf + 2 * D;
    float* cb_lc = fbuf + 3 * D;

    // Bs/Bd transposes (exact f32 halves) + layer-3 converts in one launch
    prep_k<<<dim3(D / TT, D / TT, 4), 256, 0, stream>>>(lcs, ucs, BsT, BdT, Ga, Gc);
    // lb0/ub0 + cb init (layer-3 bias + j=2 bias update), pure f32
    vec_k<<<dim3(4 * D / 4), 256, 0, stream>>>(lb, ub, lcs, ucs, lcb, ucb, lb0, ub0, cb_uc, cb_lc);

    u16* curU = Ga; u16* curL = Gc;
    u16* altU = Gb; u16* altL = Gd;
    for (int j = 2; j >= 0; --j) {
        const float* ucbN = (j > 0) ? (ucb + (size_t)(j - 1) * D) : ub0;
        const float* lcbN = (j > 0) ? (lcb + (size_t)(j - 1) * D) : lb0;
        u16* oU = (j > 0) ? altU : (u16*)nullptr;   // j=0: final apply fused, no store
        u16* oL = (j > 0) ? altL : (u16*)nullptr;
        gemm_step<<<dim3(16, 16, 2), 256, 0, stream>>>(
            curU, curL, BsT + (size_t)j * DD, BdT + (size_t)j * DD, oU, oL,
            ucbN, lcbN, cb_uc, cb_lc);
        u16* t;
        t = curU; curU = altU; altU = t;
        t = curL; curL = altL; altL = t;
    }
    // out = cb (bias chain + final rowdots, all accumulated in f32)
    emit_k<<<dim3((2 * D + 255) / 256), 256, 0, stream>>>(cb_uc, cb_lc, out);
}

// Round 14
// 127.424 us; speedup vs baseline: 1.0191x; 1.0191x over previous
//
#include <hip/hip_runtime.h>

#define D 1536
#define BT 96          // square output tile
#define BK 64          // K-step
#define NT (D / BK)    // 24 K-steps
#define TT 64
#define TILE_E (BT * BK)       // 6144 elements per staged tile (12 KiB)
#define BUF_E (3 * TILE_E)     // A | Bs | Bd per buffer (36 KiB)

typedef unsigned short u16;
typedef short bf16x8 __attribute__((ext_vector_type(8)));
typedef float f32x4 __attribute__((ext_vector_type(4)));

static __device__ __forceinline__ u16 f2bf(float f) {
    unsigned u; __builtin_memcpy(&u, &f, 4);
    unsigned r = (u + 0x7FFFu + ((u >> 16) & 1u)) >> 16;
    return (u16)r;
}
static __device__ __forceinline__ float bf2f(u16 s) {
    unsigned u = ((unsigned)s) << 16;
    float f; __builtin_memcpy(&f, &u, 4); return f;
}

#define GLDS(g, s) __builtin_amdgcn_global_load_lds( \
    (const __attribute__((address_space(1))) void*)(g), \
    (__attribute__((address_space(3))) void*)(s), 16, 0, 0)

#define MFMA16(a, b, c) __builtin_amdgcn_mfma_f32_16x16x32_bf16(a, b, c, 0, 0, 0)

// ---------------- prep ----------------
// z=0..2: layer z: BsT[z] = bf16((ucs[z]+lcs[z])/2)^T, BdT[z] = bf16((ucs[z]-lcs[z])/2)^T
// z=3:    convert ucs[3]->Ga, lcs[3]->Gc (bf16, untransposed)
__global__ __launch_bounds__(256) void prep_k(
    const float* __restrict__ lcs, const float* __restrict__ ucs,
    u16* __restrict__ BsT, u16* __restrict__ BdT,
    u16* __restrict__ Ga, u16* __restrict__ Gc)
{
    const int z = blockIdx.z;
    const int r0 = blockIdx.y * TT, c0 = blockIdx.x * TT;
    const int tid = threadIdx.x;

    if (z == 3) {
#pragma unroll
        for (int m = 0; m < 2; ++m) {
            const float* src = (m ? lcs : ucs) + (size_t)3 * D * D;
            u16* dst = m ? Gc : Ga;
#pragma unroll
            for (int i = 0; i < 2; ++i) {
                int r = (tid >> 3) + i * 32, cc = (tid & 7) * 8;
                const float* p = src + (size_t)(r0 + r) * D + c0 + cc;
                f32x4 x0 = *(const f32x4*)p;
                f32x4 x1 = *(const f32x4*)(p + 4);
                bf16x8 y;
#pragma unroll
                for (int e = 0; e < 4; ++e) { y[e] = (short)f2bf(x0[e]); y[e + 4] = (short)f2bf(x1[e]); }
                *(bf16x8*)(dst + (size_t)(r0 + r) * D + c0 + cc) = y;
            }
        }
        return;
    }

    __shared__ u16 ts[TT][TT + 8];
    __shared__ u16 td[TT][TT + 8];
    const float* srcl = lcs + (size_t)z * D * D;
    const float* srcu = ucs + (size_t)z * D * D;
#pragma unroll
    for (int i = 0; i < 2; ++i) {
        int c = tid + i * 256; int r = c >> 3, v = c & 7;
        size_t off = (size_t)(r0 + r) * D + c0 + v * 8;
        f32x4 l0 = *(const f32x4*)(srcl + off);
        f32x4 l1 = *(const f32x4*)(srcl + off + 4);
        f32x4 u0 = *(const f32x4*)(srcu + off);
        f32x4 u1 = *(const f32x4*)(srcu + off + 4);
        bf16x8 ys, yd;
#pragma unroll
        for (int e = 0; e < 4; ++e) {
            ys[e]     = (short)f2bf((u0[e] + l0[e]) * 0.5f);
            yd[e]     = (short)f2bf((u0[e] - l0[e]) * 0.5f);
            ys[e + 4] = (short)f2bf((u1[e] + l1[e]) * 0.5f);
            yd[e + 4] = (short)f2bf((u1[e] - l1[e]) * 0.5f);
        }
        *(bf16x8*)&ts[r][v * 8] = ys;
        *(bf16x8*)&td[r][v * 8] = yd;
    }
    __syncthreads();
#pragma unroll
    for (int i = 0; i < 2; ++i) {
        int c = tid + i * 256; int rr = c >> 3, v = c & 7;
        bf16x8 xs, xd;
#pragma unroll
        for (int e = 0; e < 8; ++e) { xs[e] = (short)ts[v * 8 + e][rr]; xd[e] = (short)td[v * 8 + e][rr]; }
        size_t off = (size_t)z * D * D + (size_t)(c0 + rr) * D + r0 + v * 8;
        *(bf16x8*)(BsT + off) = xs;
        *(bf16x8*)(BdT + off) = xd;
    }
}

// ---------------- vec: lb0/ub0 rows + cb init (layer-3 bias + j=2 bias update), all f32 ----------------
__global__ __launch_bounds__(256) void vec_k(
    const float* __restrict__ lb, const float* __restrict__ ub,
    const float* __restrict__ lcs, const float* __restrict__ ucs,
    const float* __restrict__ lcb, const float* __restrict__ ucb,
    float* __restrict__ lb0, float* __restrict__ ub0,
    float* __restrict__ cb_uc, float* __restrict__ cb_lc)
{
    const int tt = blockIdx.x * 4 + (threadIdx.x >> 6);
    const int lane = threadIdx.x & 63;
    const int which = tt / D;           // 0:lb0 1:ub0 2:cb_uc 3:cb_lc
    const int row_n = tt - which * D;

    const float* row; const float* vp; const float* vn;
    if (which == 0)      { row = lcs + (size_t)row_n * D;               vp = lb;           vn = ub; }
    else if (which == 1) { row = ucs + (size_t)row_n * D;               vp = ub;           vn = lb; }
    else if (which == 2) { row = ucs + (size_t)(3 * (size_t)D * D) + (size_t)row_n * D; vp = ucb + 2 * D; vn = lcb + 2 * D; }
    else                 { row = lcs + (size_t)(3 * (size_t)D * D) + (size_t)row_n * D; vp = lcb + 2 * D; vn = ucb + 2 * D; }

    float s = 0.f;
    for (int c2 = 0; c2 < D / 256; ++c2) {
        int base = (c2 * 64 + lane) * 4;
        f32x4 g = *(const f32x4*)(row + base);
        f32x4 p = *(const f32x4*)(vp + base);
        f32x4 m = *(const f32x4*)(vn + base);
#pragma unroll
        for (int e = 0; e < 4; ++e) s += g[e] * (g[e] > 0.f ? p[e] : m[e]);
    }
#pragma unroll
    for (int o = 32; o; o >>= 1) s += __shfl_down(s, o);
    if (lane == 0) {
        if (which == 0)      lb0[row_n] = s + lcb[row_n];
        else if (which == 1) ub0[row_n] = s + ucb[row_n];
        else if (which == 2) cb_uc[row_n] = s + ucb[3 * D + row_n];
        else                 cb_lc[row_n] = s + lcb[3 * D + row_n];
    }
}

// ---------------- GEMM step: out = A@Bs + sgn(|A|)@Bd ----------------
// chain 0 (uc): out = Guc@Bs + |Guc|@Bd ; chain 1 (lc): out = Glc@Bs - |Glc|@Bd.
// 96x96 tile, 4 waves (2x2), per-wave 48x48. T3-minimum single-barrier
// schedule: {STAGE(t+1 -> other buf); ds_read(t)+MFMA; vmcnt(0); barrier}.
// Race-free with 2 buffers: after barrier(t-1) all waves' reads of
// buf[(t-1)&1] are complete (lgkm waits precede the consuming MFMAs), so
// iter t's STAGE into that buffer is safe. XOR swizzle slot^(row&7) via
// pre-swizzled global source (rule #21). XCD-aware block swizzle (R9).
// Fused epilogue: rowdot(acc, vp/vn) -> atomicAdd cb (j>0: bias recurrence;
// j=0: ub0/lb0 final apply, stores skipped).
__global__ __launch_bounds__(256, 2) void gemm_step(
    const u16* __restrict__ Guc, const u16* __restrict__ Glc,
    const u16* __restrict__ Bs, const u16* __restrict__ Bd,
    u16* __restrict__ outU, u16* __restrict__ outL,
    const float* __restrict__ ucbN, const float* __restrict__ lcbN,
    float* __restrict__ cb_uc, float* __restrict__ cb_lc)
{
    __shared__ u16 smem[2 * BUF_E];          // 2 x 36 KiB
    // ---- XCD swizzle: wgid linear (x fastest) -> (bx, by, chain) ----
    const int wg  = blockIdx.x + 16 * blockIdx.y + 256 * blockIdx.z;  // 0..511
    const int xcd = wg & 7, idx = wg >> 3;                            // 64 wgs per XCD
    const int chain = xcd >> 2;
    const int bx = (xcd & 1) * 8 + (idx & 7);
    const int by = ((xcd >> 1) & 1) * 8 + (idx >> 3);

    const u16* A = chain ? Glc : Guc;
    u16* out = chain ? outL : outU;
    const unsigned sgn = chain ? 0x80008000u : 0u;   // -|A| for lc chain
    const int r0 = by * BT, c0 = bx * BT;
    const int tid = threadIdx.x, lane = tid & 63, wid = tid >> 6;
    const int mb = (wid >> 1) * 48, nb = (wid & 1) * 48;
    const int lrow = lane & 15, lk = lane >> 4;

    f32x4 acc[3][3] = {};

    // staging: 9 chunks of 16B per thread; chunk c=(i%3)*256+tid -> row c>>3,
    // kc=tid&7, global k-slot pre-swizzled kcg = kc ^ (row&7)
#define STAGE(kt, sbuf) do { \
    _Pragma("unroll") for (int i_ = 0; i_ < 9; ++i_) { \
        const int idx_ = (i_ % 3) * 256 + tid; \
        const int row_ = idx_ >> 3; \
        const int kcg_ = (tid & 7) ^ (row_ & 7); \
        const u16* base_ = (i_ < 3) ? (A + (size_t)(r0 + row_) * D) \
                        : ((i_ < 6) ? (Bs + (size_t)(c0 + row_) * D) \
                                    : (Bd + (size_t)(c0 + row_) * D)); \
        GLDS(base_ + (kt) + kcg_ * 8, (char*)(sbuf) + (i_ * 256 + wid * 64) * 16); \
    } } while (0)

    // prologue: stage tile 0, drain, barrier
    STAGE(0, smem);
    asm volatile("s_waitcnt vmcnt(0)" ::: "memory");
    __builtin_amdgcn_s_barrier();

#pragma unroll 1
    for (int t = 0; t < NT; ++t) {
        // issue next tile's loads first (hidden under this tile's compute)
        if (t + 1 < NT)
            STAGE((t + 1) * BK, smem + ((t + 1) & 1) * BUF_E);

        const u16* sb = smem + (t & 1) * BUF_E;
#pragma unroll
        for (int ks = 0; ks < 2; ++ks) {
            const int slot = ks * 4;
            bf16x8 a[3], x[3];
#pragma unroll
            for (int mi = 0; mi < 3; ++mi) {
                int row = mb + mi * 16 + lrow;
                a[mi] = *(const bf16x8*)(sb + row * BK + ((slot + lk) ^ (row & 7)) * 8);
                union { bf16x8 v; unsigned u[4]; } ti, to;
                ti.v = a[mi];
#pragma unroll
                for (int q = 0; q < 4; ++q) to.u[q] = (ti.u[q] & 0x7FFF7FFFu) ^ sgn;
                x[mi] = to.v;
            }
#pragma unroll
            for (int ni = 0; ni < 3; ++ni) {
                int row = nb + ni * 16 + lrow;
                int o = row * BK + ((slot + lk) ^ (row & 7)) * 8;
                bf16x8 bs = *(const bf16x8*)(sb + TILE_E + o);
                bf16x8 bd = *(const bf16x8*)(sb + 2 * TILE_E + o);
#pragma unroll
                for (int mi = 0; mi < 3; ++mi) {
                    acc[mi][ni] = MFMA16(a[mi], bs, acc[mi][ni]);
                    acc[mi][ni] = MFMA16(x[mi], bd, acc[mi][ni]);
                }
            }
        }
        // single per-iteration sync: next tile landed + all waves done reading
        asm volatile("s_waitcnt vmcnt(0)" ::: "memory");
        __builtin_amdgcn_sched_barrier(0);
        __builtin_amdgcn_s_barrier();
    }

    // fused epilogue: rowdot(acc, select(vp,vn)) accumulated into cb.
    {
        const float* pb_ = chain ? lcbN : ucbN;
        const float* nb_ = chain ? ucbN : lcbN;
        float* cb = chain ? cb_lc : cb_uc;
        float pbv[3], nbv[3];
#pragma unroll
        for (int ni = 0; ni < 3; ++ni) {
            int c = c0 + nb + ni * 16 + lrow;
            pbv[ni] = pb_[c]; nbv[ni] = nb_[c];
        }
#pragma unroll
        for (int mi = 0; mi < 3; ++mi)
#pragma unroll
            for (int q = 0; q < 4; ++q) {
                float s = 0.f;
#pragma unroll
                for (int ni = 0; ni < 3; ++ni) {
                    float g = acc[mi][ni][q];
                    s += g * (g > 0.f ? pbv[ni] : nbv[ni]);
                }
                s += __shfl_xor(s, 1); s += __shfl_xor(s, 2);
                s += __shfl_xor(s, 4); s += __shfl_xor(s, 8);
                if (lrow == 0)
                    atomicAdd(&cb[r0 + mb + mi * 16 + lk * 4 + q], s);
            }
    }

    if (out) {
#pragma unroll
        for (int mi = 0; mi < 3; ++mi)
#pragma unroll
            for (int ni = 0; ni < 3; ++ni) {
                int c = c0 + nb + ni * 16 + lrow;
                int rbase = r0 + mb + mi * 16 + lk * 4;
#pragma unroll
                for (int q = 0; q < 4; ++q)
                    out[(size_t)(rbase + q) * D + c] = f2bf(acc[mi][ni][q]);
            }
    }
#undef STAGE
}

// ---------------- emit: out[0..D) = cb_lc (cur_lb), out[D..2D) = cb_uc (cur_ub) ----------------
__global__ __launch_bounds__(256) void emit_k(
    const float* __restrict__ cb_uc, const float* __restrict__ cb_lc,
    float* __restrict__ out)
{
    int i = blockIdx.x * 256 + threadIdx.x;
    if (i < D)          out[i] = cb_lc[i];
    else if (i < 2 * D) out[i] = cb_uc[i - D];
}

extern "C" void kernel_launch(void* const* d_in, const int* in_sizes, int n_in,
                              void* d_out, int out_size, void* d_ws, size_t ws_size,
                              hipStream_t stream) {
    const float* lb  = (const float*)d_in[0];
    const float* ub  = (const float*)d_in[1];
    const float* lcs = (const float*)d_in[2];
    const float* ucs = (const float*)d_in[3];
    const float* lcb = (const float*)d_in[4];
    const float* ucb = (const float*)d_in[5];
    float* out = (float*)d_out;

    const size_t DD = (size_t)D * D;
    u16* ws   = (u16*)d_ws;
    u16* BsT = ws;                  // 3*D*D bf16, [N][K] layout
    u16* BdT = BsT + 3 * DD;        // 3*D*D bf16
    u16* Ga = BdT + 3 * DD;         // G ping-pong buffers (bf16)
    u16* Gb = Ga + DD;
    u16* Gc = Gb + DD;
    u16* Gd = Gc + DD;
    float* fbuf  = (float*)(Gd + DD);
    float* lb0   = fbuf;
    float* ub0   = fbuf + D;
    float* cb_uc = fbuf + 2 * D;
    float* cb_lc = fbuf + 3 * D;

    // Bs/Bd transposes (exact f32 halves) + layer-3 converts in one launch
    prep_k<<<dim3(D / TT, D / TT, 4), 256, 0, stream>>>(lcs, ucs, BsT, BdT, Ga, Gc);
    // lb0/ub0 + cb init (layer-3 bias + j=2 bias update), pure f32
    vec_k<<<dim3(4 * D / 4), 256, 0, stream>>>(lb, ub, lcs, ucs, lcb, ucb, lb0, ub0, cb_uc, cb_lc);

    u16* curU = Ga; u16* curL = Gc;
    u16* altU = Gb; u16* altL = Gd;
    for (int j = 2; j >= 0; --j) {
        const float* ucbN = (j > 0) ? (ucb + (size_t)(j - 1) * D) : ub0;
        const float* lcbN = (j > 0) ? (lcb + (size_t)(j - 1) * D) : lb0;
        u16* oU = (j > 0) ? altU : (u16*)nullptr;   // j=0: final apply fused, no store
        u16* oL = (j > 0) ? altL : (u16*)nullptr;
        gemm_step<<<dim3(16, 16, 2), 256, 0, stream>>>(
            curU, curL, BsT + (size_t)j * DD, BdT + (size_t)j * DD, oU, oL,
            ucbN, lcbN, cb_uc, cb_lc);
        u16* t;
        t = curU; curU = altU; altU = t;
        t = curL; curL = altL; altL = t;
    }
    // out = cb (bias chain + final rowdots, all accumulated in f32)
    emit_k<<<dim3((2 * D + 255) / 256), 256, 0, stream>>>(cb_uc, cb_lc, out);
}